// Round 7
// baseline (376.273 us; speedup 1.0000x reference)
//
#include <hip/hip_runtime.h>
#include <hip/hip_bf16.h>
#include <math.h>

#define BB  2
#define TT  2048
#define DDE 1024
#define NHH 16
#define HDD 64

typedef __bf16 bf16_t;
typedef __attribute__((ext_vector_type(8))) __bf16 bf16x8;
typedef __attribute__((ext_vector_type(4))) __bf16 bf16x4;
typedef __attribute__((ext_vector_type(4))) float  f32x4;

#define MFMA(a, b, c) __builtin_amdgcn_mfma_f32_16x16x32_bf16((a), (b), (c), 0, 0, 0)

__device__ inline unsigned short bf2us(bf16_t x) {
    union { bf16_t h; unsigned short u; } c; c.h = x; return c.u;
}

__device__ inline void gll16(const bf16_t* g, unsigned short* l) {
    __builtin_amdgcn_global_load_lds(
        (const __attribute__((address_space(1))) void*)g,
        (__attribute__((address_space(3))) void*)l, 16, 0, 0);
}

// Stage [ROWS x 64] bf16 tile into LDS via global_load_lds, chunk-swizzled.
template<int ROWS>
__device__ inline void stage_tile(const bf16_t* g0, size_t gstride,
                                  unsigned short* lds, int wave, int lane)
{
    const int r8 = lane >> 3;
    const int ck = (lane & 7) ^ r8;
    constexpr int RW = ROWS / 4;
    const bf16_t* g = g0 + (size_t)(wave * RW + r8) * gstride + ck * 8;
    unsigned short* l = lds + wave * RW * 64 + lane * 8;
    #pragma unroll
    for (int i = 0; i < RW / 8; ++i)
        gll16(g + (size_t)(i * 8) * gstride, l + i * 512);
}

// split-s: 40 blocks cover 16 q-tiles x ceil(tiles/8) chunks (chunk = 8 tiles)
__device__ inline void split_decode(int wid, int& qt, int& ch) {
    const int g = (wid >= 24) ? 3 : (wid >= 12) ? 2 : (wid >= 4) ? 1 : 0;
    const int loc = wid - 2 * g * (g + 1);
    qt = 4 * g + loc / (g + 1);
    ch = loc % (g + 1);
}

// ---------------------------------------------------------------------------
__global__ __launch_bounds__(256) void cvt_all(
    const float* __restrict__ x, const float* __restrict__ wa,
    const float* __restrict__ wk, const float* __restrict__ wp,
    bf16_t* __restrict__ out)
{
    const size_t NX  = (size_t)BB*TT*DDE;
    const size_t NWA = (size_t)2*DDE*DDE;
    const size_t NW  = (size_t)DDE*DDE;
    const size_t e = ((size_t)blockIdx.x * 256 + threadIdx.x) * 4;
    const float* src;
    if (e < NX)                 src = x  + e;
    else if (e < NX + NWA)      src = wa + (e - NX);
    else if (e < NX + NWA + NW) src = wk + (e - NX - NWA);
    else                        src = wp + (e - NX - NWA - NW);
    float4 v = *(const float4*)src;
    bf16x4 o;
    o[0] = (bf16_t)v.x; o[1] = (bf16_t)v.y;
    o[2] = (bf16_t)v.z; o[3] = (bf16_t)v.w;
    *(bf16x4*)(out + e) = o;
}

// ---------------------------------------------------------------------------
// Per-head 64x64 transpose: dst[bh][d][t] = src[b][t][h*64+d].
// ---------------------------------------------------------------------------
__global__ __launch_bounds__(256) void transpose_head(
    const bf16_t* __restrict__ src, bf16_t* __restrict__ dst)
{
    const int t0 = blockIdx.x * 64, h = blockIdx.y, b = blockIdx.z;
    const int tid = threadIdx.x;
    __shared__ __align__(16) bf16_t tile[64 * 64];

    #pragma unroll
    for (int it = 0; it < 2; ++it) {
        const int t = it * 32 + (tid >> 3);
        const int cw = tid & 7;
        const int slot = (cw + (t >> 3)) & 7;
        bf16x8 v = *(const bf16x8*)(src + (size_t)(b*TT + t0 + t)*DDE + h*HDD + cw*8);
        *(bf16x8*)(tile + t*64 + slot*8) = v;
    }
    __syncthreads();
    const int bh = b * NHH + h;
    #pragma unroll
    for (int it = 0; it < 2; ++it) {
        const int d = it * 32 + (tid >> 3);
        const int co = tid & 7;
        const int slot = ((d >> 3) + co) & 7;
        bf16x8 o;
        #pragma unroll
        for (int j = 0; j < 8; ++j)
            o[j] = tile[(co*8 + j)*64 + slot*8 + (d & 7)];
        *(bf16x8*)(dst + (size_t)(bh*64 + d)*TT + t0 + co*8) = o;
    }
}

// ---------------------------------------------------------------------------
// Fused normalize + E-transpose.
// ---------------------------------------------------------------------------
__global__ __launch_bounds__(256) void norm_build_etg(
    const float* __restrict__ yo, const float* __restrict__ ls,
    const bf16_t* __restrict__ xb, bf16_t* __restrict__ yarb,
    bf16_t* __restrict__ etg)
{
    const int t0 = blockIdx.x * 64, h = blockIdx.y, b = blockIdx.z;
    const int tid = threadIdx.x;
    const int bh = b * NHH + h;
    __shared__ __align__(16) bf16_t tile[64 * 64];

    #pragma unroll
    for (int it = 0; it < 2; ++it) {
        const int t = it * 32 + (tid >> 3);
        const int cw = tid & 7;
        const int slot = (cw + (t >> 3)) & 7;
        const int tg = t0 + t;
        const float inv = 1.f / ls[(size_t)bh*TT + tg];
        const float* yp = yo + (size_t)(b*TT + tg)*DDE + h*HDD + cw*8;
        float4 y0 = *(const float4*)yp;
        float4 y1 = *(const float4*)(yp + 4);
        bf16x8 nb;
        nb[0] = (bf16_t)(y0.x*inv); nb[1] = (bf16_t)(y0.y*inv);
        nb[2] = (bf16_t)(y0.z*inv); nb[3] = (bf16_t)(y0.w*inv);
        nb[4] = (bf16_t)(y1.x*inv); nb[5] = (bf16_t)(y1.y*inv);
        nb[6] = (bf16_t)(y1.z*inv); nb[7] = (bf16_t)(y1.w*inv);
        *(bf16x8*)(yarb + (size_t)(b*TT + tg)*DDE + h*HDD + cw*8) = nb;
        bf16x8 ev;
        if (tg == 0) {
            #pragma unroll
            for (int u = 0; u < 8; ++u) ev[u] = (bf16_t)0.f;
        } else {
            const float invp = 1.f / ls[(size_t)bh*TT + tg - 1];
            const float* ypp = yo + (size_t)(b*TT + tg - 1)*DDE + h*HDD + cw*8;
            float4 p0 = *(const float4*)ypp;
            float4 p1 = *(const float4*)(ypp + 4);
            bf16x8 xv = *(const bf16x8*)(xb + (size_t)(b*TT + tg)*DDE + h*HDD + cw*8);
            ev[0] = (bf16_t)((float)xv[0] - p0.x*invp);
            ev[1] = (bf16_t)((float)xv[1] - p0.y*invp);
            ev[2] = (bf16_t)((float)xv[2] - p0.z*invp);
            ev[3] = (bf16_t)((float)xv[3] - p0.w*invp);
            ev[4] = (bf16_t)((float)xv[4] - p1.x*invp);
            ev[5] = (bf16_t)((float)xv[5] - p1.y*invp);
            ev[6] = (bf16_t)((float)xv[6] - p1.z*invp);
            ev[7] = (bf16_t)((float)xv[7] - p1.w*invp);
        }
        *(bf16x8*)(tile + t*64 + slot*8) = ev;
    }
    __syncthreads();
    #pragma unroll
    for (int it = 0; it < 2; ++it) {
        const int d = it * 32 + (tid >> 3);
        const int co = tid & 7;
        const int slot = ((d >> 3) + co) & 7;
        bf16x8 o;
        #pragma unroll
        for (int j = 0; j < 8; ++j)
            o[j] = tile[(co*8 + j)*64 + slot*8 + (d & 7)];
        *(bf16x8*)(etg + (size_t)(bh*64 + d)*TT + t0 + co*8) = o;
    }
}

// ---------------------------------------------------------------------------
// Fused QKV GEMM, BK=64 swizzled staging (as R5).
// ---------------------------------------------------------------------------
__global__ __launch_bounds__(256) void gemm_qkk2(
    const bf16_t* __restrict__ A, const bf16_t* __restrict__ wab,
    const bf16_t* __restrict__ wkb, const float* __restrict__ b_attn,
    const float* __restrict__ b_k2, bf16_t* __restrict__ qkb,
    bf16_t* __restrict__ qab, bf16_t* __restrict__ kcs)
{
    __shared__ __align__(16) unsigned short As[128 * 64];
    __shared__ __align__(16) unsigned short Bs[128 * 64];
    const int tid  = threadIdx.x;
    const int wave = tid >> 6, lane = tid & 63;
    const int l15  = lane & 15, quad = lane >> 4;
    const int bm = blockIdx.y * 128, bn = blockIdx.x * 128;
    const int wm = (wave & 1) * 64, wn = (wave >> 1) * 64;
    const int region = bn >> 10;
    const int K = DDE;

    const bf16_t* W = (region < 2) ? wab + (size_t)bn * K
                                   : wkb + (size_t)(bn - 2048) * K;
    const float* bp = (region < 2) ? b_attn + bn : b_k2 + (bn - 2048);
    const bf16_t* Ab = A + (size_t)bm * K;

    f32x4 acc[4][4];
    #pragma unroll
    for (int i = 0; i < 4; ++i)
        #pragma unroll
        for (int j = 0; j < 4; ++j) acc[i][j] = (f32x4)0.f;

    for (int k0 = 0; k0 < K; k0 += 64) {
        __syncthreads();
        stage_tile<128>(Ab + k0, K, As, wave, lane);
        stage_tile<128>(W  + k0, K, Bs, wave, lane);
        __syncthreads();
        bf16x8 af[4][2], bfr[4][2];
        #pragma unroll
        for (int mt = 0; mt < 4; ++mt)
            #pragma unroll
            for (int kh = 0; kh < 2; ++kh)
                af[mt][kh] = *(const bf16x8*)(As + (wm + mt*16 + l15)*64
                                              + (((kh*4 + quad) ^ (l15 & 7))*8));
        #pragma unroll
        for (int nt = 0; nt < 4; ++nt)
            #pragma unroll
            for (int kh = 0; kh < 2; ++kh)
                bfr[nt][kh] = *(const bf16x8*)(Bs + (wn + nt*16 + l15)*64
                                               + (((kh*4 + quad) ^ (l15 & 7))*8));
        #pragma unroll
        for (int mt = 0; mt < 4; ++mt)
            #pragma unroll
            for (int nt = 0; nt < 4; ++nt) {
                acc[mt][nt] = MFMA(af[mt][0], bfr[nt][0], acc[mt][nt]);
                acc[mt][nt] = MFMA(af[mt][1], bfr[nt][1], acc[mt][nt]);
            }
    }

    #pragma unroll
    for (int nt = 0; nt < 4; ++nt) {
        const int cl = wn + nt*16 + l15;
        const float bj = bp[cl];
        const int cg = bn + cl;
        #pragma unroll
        for (int mt = 0; mt < 4; ++mt)
            #pragma unroll
            for (int r = 0; r < 4; ++r) {
                const int row = bm + wm + mt*16 + quad*4 + r;
                const float v = acc[mt][nt][r] + bj;
                if (region == 0) {
                    qkb[(size_t)row * (2*DDE) + cg] = (bf16_t)(v * 0.180336880f);
                    const float z = v * 0.125f;
                    qab[(size_t)row * DDE + cg] = (bf16_t)((v > 0.f) ? 0.02f*z : z);
                } else if (region == 1) {
                    qkb[(size_t)row * (2*DDE) + cg] = (bf16_t)v;
                } else {
                    const int c2 = cg - 2048;
                    const float kc = 1.f/(1.f + __expf(-v*0.0025f)) - 0.5f;
                    if (((row + 1) & (TT - 1)) != 0)
                        kcs[(size_t)(row + 1) * DDE + c2] = (bf16_t)kc;
                    if ((row & (TT - 1)) == 0)
                        kcs[(size_t)row * DDE + c2] = (bf16_t)0.f;
                }
            }
    }
}

// ---------------------------------------------------------------------------
// proj GEMM, 128x128 tile (R5 version), BK=64, fp32 out.
// ---------------------------------------------------------------------------
__global__ __launch_bounds__(256) void gemm_proj(
    const bf16_t* __restrict__ A, const bf16_t* __restrict__ W,
    const float* __restrict__ bias, float* __restrict__ C,
    int M, int N, int K, float bmul)
{
    __shared__ __align__(16) unsigned short As[128 * 64];
    __shared__ __align__(16) unsigned short Bs[128 * 64];
    const int tid  = threadIdx.x;
    const int wave = tid >> 6, lane = tid & 63;
    const int l15  = lane & 15, quad = lane >> 4;
    const int bm = blockIdx.y * 128, bn = blockIdx.x * 128;
    const int wm = (wave & 1) * 64, wn = (wave >> 1) * 64;

    const bf16_t* Ab = A + (size_t)bm * K;
    const bf16_t* Wb = W + (size_t)bn * K;

    f32x4 acc[4][4];
    #pragma unroll
    for (int i = 0; i < 4; ++i)
        #pragma unroll
        for (int j = 0; j < 4; ++j) acc[i][j] = (f32x4)0.f;

    for (int k0 = 0; k0 < K; k0 += 64) {
        __syncthreads();
        stage_tile<128>(Ab + k0, K, As, wave, lane);
        stage_tile<128>(Wb + k0, K, Bs, wave, lane);
        __syncthreads();
        bf16x8 af[4][2], bfr[4][2];
        #pragma unroll
        for (int mt = 0; mt < 4; ++mt)
            #pragma unroll
            for (int kh = 0; kh < 2; ++kh)
                af[mt][kh] = *(const bf16x8*)(As + (wm + mt*16 + l15)*64
                                              + (((kh*4 + quad) ^ (l15 & 7))*8));
        #pragma unroll
        for (int nt = 0; nt < 4; ++nt)
            #pragma unroll
            for (int kh = 0; kh < 2; ++kh)
                bfr[nt][kh] = *(const bf16x8*)(Bs + (wn + nt*16 + l15)*64
                                               + (((kh*4 + quad) ^ (l15 & 7))*8));
        #pragma unroll
        for (int mt = 0; mt < 4; ++mt)
            #pragma unroll
            for (int nt = 0; nt < 4; ++nt) {
                acc[mt][nt] = MFMA(af[mt][0], bfr[nt][0], acc[mt][nt]);
                acc[mt][nt] = MFMA(af[mt][1], bfr[nt][1], acc[mt][nt]);
            }
    }

    #pragma unroll
    for (int nt = 0; nt < 4; ++nt) {
        const int col = bn + wn + nt*16 + l15;
        const float bj = bias[col] * bmul;
        #pragma unroll
        for (int mt = 0; mt < 4; ++mt)
            #pragma unroll
            for (int r = 0; r < 4; ++r) {
                const int row = bm + wm + mt*16 + quad*4 + r;
                C[(size_t)row * N + col] = acc[mt][nt][r] + bj;
            }
    }
}

// ---------------------------------------------------------------------------
// AR: fixed-max flash attention, barrier-free.  All Q/K/V^T fragments loaded
// directly global->VGPR (coalesced 16-row x 64B per b128); only the P
// transpose round-trips through wave-private LDS (lgkmcnt, no barrier).
// ---------------------------------------------------------------------------
__global__ __launch_bounds__(256) void attn_ar_mfma(
    const bf16_t* __restrict__ qkb, const bf16_t* __restrict__ vtg,
    float* __restrict__ yo, float* __restrict__ lsum)
{
    int qt, ch;
    split_decode(39 - (int)blockIdx.x, qt, ch);
    const int h = blockIdx.y, b = blockIdx.z;
    const int tid = threadIdx.x, wave = tid >> 6, lane = tid & 63;
    const int l15 = lane & 15, quad = lane >> 4;
    const int q0 = qt * 128;
    const int bh = b * NHH + h;

    __shared__ __align__(16) unsigned short Pw[4][32 * 72];
    unsigned short* pw = Pw[wave];

    const int qw0 = q0 + wave * 32;

    // Q A-frags direct (rows qw0 + mt*16 + l15, k = kc*32 + quad*8)
    bf16x8 qf[2][2];
    {
        const bf16_t* qp = qkb + (size_t)(b*TT + qw0 + l15)*(2*DDE) + h*HDD + quad*8;
        qf[0][0] = *(const bf16x8*)(qp);
        qf[0][1] = *(const bf16x8*)(qp + 32);
        qf[1][0] = *(const bf16x8*)(qp + (size_t)16*(2*DDE));
        qf[1][1] = *(const bf16x8*)(qp + (size_t)16*(2*DDE) + 32);
    }

    f32x4 o[2][4];
    float lrow[2][4];
    #pragma unroll
    for (int mt = 0; mt < 2; ++mt) {
        #pragma unroll
        for (int nt = 0; nt < 4; ++nt) o[mt][nt] = (f32x4)0.f;
        #pragma unroll
        for (int r = 0; r < 4; ++r) lrow[mt][r] = 0.f;
    }

    const int kt0 = ch * 8;
    const int kt1 = min(kt0 + 8, 2*qt + 2);
    const int ktw = min(kt1, (qw0 + 32 + 63) >> 6);   // wave's causal bound

    for (int kt = kt0; kt < ktw; ++kt) {
        const int s0 = kt * 64;
        // K B-frags (rows s0+nt*16+l15)
        const bf16_t* kp = qkb + (size_t)(b*TT + s0 + l15)*(2*DDE) + DDE + h*HDD + quad*8;
        bf16x8 kb[4][2];
        #pragma unroll
        for (int nt = 0; nt < 4; ++nt) {
            kb[nt][0] = *(const bf16x8*)(kp + (size_t)(nt*16)*(2*DDE));
            kb[nt][1] = *(const bf16x8*)(kp + (size_t)(nt*16)*(2*DDE) + 32);
        }
        // V^T B-frags (rows d = nt*16+l15, cols s0 + sc*32 + quad*8)
        const bf16_t* vp = vtg + (size_t)(bh*64 + l15)*TT + s0 + quad*8;
        bf16x8 vb[4][2];
        #pragma unroll
        for (int nt = 0; nt < 4; ++nt) {
            vb[nt][0] = *(const bf16x8*)(vp + (size_t)(nt*16)*TT);
            vb[nt][1] = *(const bf16x8*)(vp + (size_t)(nt*16)*TT + 32);
        }
        // S = Q K^T
        f32x4 sv[2][4];
        #pragma unroll
        for (int nt = 0; nt < 4; ++nt)
            #pragma unroll
            for (int mt = 0; mt < 2; ++mt) {
                f32x4 z = (f32x4)0.f;
                z = MFMA(qf[mt][0], kb[nt][0], z);
                z = MFMA(qf[mt][1], kb[nt][1], z);
                sv[mt][nt] = z;
            }
        // p = exp2(S), causal mask on diagonal tiles, pack to wave-private LDS
        const bool domask = (s0 + 63 > qw0);
        #pragma unroll
        for (int mt = 0; mt < 2; ++mt)
            #pragma unroll
            for (int r = 0; r < 4; ++r)
                #pragma unroll
                for (int nt = 0; nt < 4; ++nt) {
                    float p = exp2f(sv[mt][nt][r]);
                    if (domask) {
                        const int qg = qw0 + mt*16 + quad*4 + r;
                        const int sg = s0 + nt*16 + l15;
                        if (sg > qg) p = 0.f;
                    }
                    lrow[mt][r] += p;
                    pw[(mt*16 + quad*4 + r)*72 + nt*16 + l15] = bf2us((bf16_t)p);
                }
        bf16x8 pa[2][2];
        #pragma unroll
        for (int mt = 0; mt < 2; ++mt)
            #pragma unroll
            for (int sc = 0; sc < 2; ++sc)
                pa[mt][sc] = *(const bf16x8*)(pw + (mt*16 + l15)*72 + sc*32 + quad*8);
        // O += P V
        #pragma unroll
        for (int nt = 0; nt < 4; ++nt)
            #pragma unroll
            for (int mt = 0; mt < 2; ++mt) {
                o[mt][nt] = MFMA(pa[mt][0], vb[nt][0], o[mt][nt]);
                o[mt][nt] = MFMA(pa[mt][1], vb[nt][1], o[mt][nt]);
            }
    }

    if (kt0 < ktw) {
        #pragma unroll
        for (int mt = 0; mt < 2; ++mt)
            #pragma unroll
            for (int r = 0; r < 4; ++r) {
                float lv = lrow[mt][r];
                lv += __shfl_xor(lv, 1);
                lv += __shfl_xor(lv, 2);
                lv += __shfl_xor(lv, 4);
                lv += __shfl_xor(lv, 8);
                if (l15 == 0)
                    atomicAdd(lsum + (size_t)bh*TT + qw0 + mt*16 + quad*4 + r, lv);
            }
        #pragma unroll
        for (int mt = 0; mt < 2; ++mt)
            #pragma unroll
            for (int nt = 0; nt < 4; ++nt)
                #pragma unroll
                for (int r = 0; r < 4; ++r) {
                    const int row = qw0 + mt*16 + quad*4 + r;
                    const int col = h*HDD + nt*16 + l15;
                    atomicAdd(yo + (size_t)(b*TT + row)*DDE + col, o[mt][nt][r]);
                }
    }
}

// ---------------------------------------------------------------------------
// MA: linear causal attention, barrier-free direct-load.  Rank-1 sigmoid
// correction row-sums computed in-register via shuffles.
// ---------------------------------------------------------------------------
__global__ __launch_bounds__(256) void attn_ma_mfma(
    const bf16_t* __restrict__ qab, const bf16_t* __restrict__ kcs,
    const bf16_t* __restrict__ etg, float* __restrict__ ma)
{
    int qt, ch;
    split_decode(39 - (int)blockIdx.x, qt, ch);
    const int h = blockIdx.y, b = blockIdx.z;
    const int tid = threadIdx.x, wave = tid >> 6, lane = tid & 63;
    const int l15 = lane & 15, quad = lane >> 4;
    const int q0 = qt * 128;
    const int bh = b * NHH + h;

    __shared__ __align__(16) unsigned short Pw[4][32 * 72];
    unsigned short* pw = Pw[wave];

    const int qw0 = q0 + wave * 32;

    // qa A-frags direct
    bf16x8 qf[2][2];
    {
        const bf16_t* qp = qab + (size_t)(b*TT + qw0 + l15)*DDE + h*HDD + quad*8;
        qf[0][0] = *(const bf16x8*)(qp);
        qf[0][1] = *(const bf16x8*)(qp + 32);
        qf[1][0] = *(const bf16x8*)(qp + (size_t)16*DDE);
        qf[1][1] = *(const bf16x8*)(qp + (size_t)16*DDE + 32);
    }
    // R[q] = sum_d qa[q][d] (fp32 over the same bf16 the MFMA consumes).
    // After xor-16/32 reduce, lanes sharing l15 hold the row-sum for q=mt*16+l15;
    // redistribute to C-layout rows (q = quad*4+r) via __shfl.
    float Rr[2][4];
    #pragma unroll
    for (int mt = 0; mt < 2; ++mt) {
        float rs = 0.f;
        #pragma unroll
        for (int kc = 0; kc < 2; ++kc)
            #pragma unroll
            for (int u = 0; u < 8; ++u) rs += (float)qf[mt][kc][u];
        rs += __shfl_xor(rs, 16);
        rs += __shfl_xor(rs, 32);
        #pragma unroll
        for (int r = 0; r < 4; ++r)
            Rr[mt][r] = 0.5f * __shfl(rs, quad*4 + r);
    }

    f32x4 o[2][4];
    #pragma unroll
    for (int mt = 0; mt < 2; ++mt)
        #pragma unroll
        for (int nt = 0; nt < 4; ++nt) o[mt][nt] = (f32x4)0.f;

    const int kt0 = ch * 8;
    const int kt1 = min(kt0 + 8, 2*qt + 2);
    const int ktw = min(kt1, (qw0 + 32 + 63) >> 6);

    for (int kt = kt0; kt < ktw; ++kt) {
        const int s0 = kt * 64;
        const bf16_t* kp = kcs + (size_t)(b*TT + s0 + l15)*DDE + h*HDD + quad*8;
        bf16x8 kb[4][2];
        #pragma unroll
        for (int nt = 0; nt < 4; ++nt) {
            kb[nt][0] = *(const bf16x8*)(kp + (size_t)(nt*16)*DDE);
            kb[nt][1] = *(const bf16x8*)(kp + (size_t)(nt*16)*DDE + 32);
        }
        const bf16_t* ep = etg + (size_t)(bh*64 + l15)*TT + s0 + quad*8;
        bf16x8 eb[4][2];
        #pragma unroll
        for (int nt = 0; nt < 4; ++nt) {
            eb[nt][0] = *(const bf16x8*)(ep + (size_t)(nt*16)*TT);
            eb[nt][1] = *(const bf16x8*)(ep + (size_t)(nt*16)*TT + 32);
        }
        f32x4 sv[2][4];
        #pragma unroll
        for (int nt = 0; nt < 4; ++nt)
            #pragma unroll
            for (int mt = 0; mt < 2; ++mt) {
                f32x4 z = (f32x4)0.f;
                z = MFMA(qf[mt][0], kb[nt][0], z);
                z = MFMA(qf[mt][1], kb[nt][1], z);
                sv[mt][nt] = z;
            }
        const bool domask = (s0 + 63 > qw0);
        const bool m0 = (kt == 0);
        #pragma unroll
        for (int mt = 0; mt < 2; ++mt)
            #pragma unroll
            for (int r = 0; r < 4; ++r)
                #pragma unroll
                for (int nt = 0; nt < 4; ++nt) {
                    const int sg = s0 + nt*16 + l15;
                    float p = sv[mt][nt][r] + Rr[mt][r];
                    if (m0 && sg == 0) p = 0.f;
                    if (domask) {
                        const int qg = qw0 + mt*16 + quad*4 + r;
                        if (sg > qg) p = 0.f;
                    }
                    pw[(mt*16 + quad*4 + r)*72 + nt*16 + l15] = bf2us((bf16_t)p);
                }
        bf16x8 pa[2][2];
        #pragma unroll
        for (int mt = 0; mt < 2; ++mt)
            #pragma unroll
            for (int sc = 0; sc < 2; ++sc)
                pa[mt][sc] = *(const bf16x8*)(pw + (mt*16 + l15)*72 + sc*32 + quad*8);
        #pragma unroll
        for (int nt = 0; nt < 4; ++nt)
            #pragma unroll
            for (int mt = 0; mt < 2; ++mt) {
                o[mt][nt] = MFMA(pa[mt][0], eb[nt][0], o[mt][nt]);
                o[mt][nt] = MFMA(pa[mt][1], eb[nt][1], o[mt][nt]);
            }
    }

    if (kt0 < ktw) {
        #pragma unroll
        for (int mt = 0; mt < 2; ++mt)
            #pragma unroll
            for (int nt = 0; nt < 4; ++nt)
                #pragma unroll
                for (int r = 0; r < 4; ++r) {
                    const int row = qw0 + mt*16 + quad*4 + r;
                    const int col = h*HDD + nt*16 + l15;
                    atomicAdd(ma + (size_t)(b*TT + row)*DDE + col, o[mt][nt][r]);
                }
    }
}

// ---------------------------------------------------------------------------
__global__ __launch_bounds__(256) void combine(
    const bf16_t* __restrict__ yarb, const float* __restrict__ ma,
    bf16_t* __restrict__ ysumb)
{
    const size_t e = ((size_t)blockIdx.x * 256 + threadIdx.x) * 4;
    bf16x4 a = *(const bf16x4*)(yarb + e);
    float4 m = *(const float4*)(ma + e);
    bf16x4 o;
    o[0] = (bf16_t)((float)a[0] + m.x);
    o[1] = (bf16_t)((float)a[1] + m.y);
    o[2] = (bf16_t)((float)a[2] + m.z);
    o[3] = (bf16_t)((float)a[3] + m.w);
    *(bf16x4*)(ysumb + e) = o;
}

// ---------------------------------------------------------------------------
extern "C" void kernel_launch(void* const* d_in, const int* in_sizes, int n_in,
                              void* d_out, int out_size, void* d_ws, size_t ws_size,
                              hipStream_t stream)
{
    const float* x      = (const float*)d_in[0];
    const float* w_attn = (const float*)d_in[1];
    const float* b_attn = (const float*)d_in[2];
    const float* w_k2   = (const float*)d_in[3];
    const float* b_k2   = (const float*)d_in[4];
    const float* w_proj = (const float*)d_in[5];
    const float* b_proj = (const float*)d_in[6];

    const size_t NX  = (size_t)BB*TT*DDE;
    const size_t NWA = (size_t)2*DDE*DDE;
    const size_t NW  = (size_t)DDE*DDE;
    const size_t NQK = (size_t)BB*TT*2*DDE;

    bf16_t* xb   = (bf16_t*)d_ws;
    bf16_t* wab  = xb   + NX;
    bf16_t* wkb  = wab  + NWA;
    bf16_t* wpb  = wkb  + NW;
    bf16_t* qkb  = wpb  + NW;      // aliased by maf (f32) after attn_ar
    bf16_t* qab  = qkb  + NQK;
    bf16_t* kcs  = qab  + NX;
    bf16_t* vtg  = kcs  + NX;      // aliased by etg after attn_ar
    float*  yo   = (float*)(vtg + NX);  // aliased by ysumb after norm_build
    bf16_t* yarb = (bf16_t*)(yo + NX);
    float*  lsum = (float*)wab;    // aliases wab after gemm_qkk2
    float*  maf  = (float*)qkb;
    bf16_t* etg  = vtg;
    bf16_t* ysumb= (bf16_t*)yo;

    hipMemsetAsync(yo, 0, NX * sizeof(float), stream);

    const size_t NCVT = NX + NWA + NW + NW;
    cvt_all<<<NCVT / 1024, 256, 0, stream>>>(x, w_attn, w_k2, w_proj, xb);

    transpose_head<<<dim3(TT/64, NHH, BB), 256, 0, stream>>>(xb, vtg);

    const int M = BB * TT;
    gemm_qkk2<<<dim3(24, M/128), 256, 0, stream>>>(xb, wab, wkb, b_attn, b_k2,
                                                    qkb, qab, kcs);
    hipMemsetAsync(lsum, 0, (size_t)BB*NHH*TT * sizeof(float), stream);

    attn_ar_mfma<<<dim3(40, NHH, BB), 256, 0, stream>>>(qkb, vtg, yo, lsum);
    norm_build_etg<<<dim3(TT/64, NHH, BB), 256, 0, stream>>>(yo, lsum, xb, yarb, etg);

    hipMemsetAsync(maf, 0, NX * sizeof(float), stream);
    attn_ma_mfma<<<dim3(40, NHH, BB), 256, 0, stream>>>(qab, kcs, etg, maf);

    combine<<<NX / 1024, 256, 0, stream>>>(yarb, maf, ysumb);
    gemm_proj<<<dim3(DDE/128, M/128), 256, 0, stream>>>(ysumb, wpb, b_proj,
                                                        (float*)d_out, M, DDE, DDE, 2.f);
}

// Round 10
// 310.033 us; speedup vs baseline: 1.2137x; 1.2137x over previous
//
#include <hip/hip_runtime.h>
#include <hip/hip_bf16.h>
#include <math.h>

#define BB  2
#define TT  2048
#define DDE 1024
#define NHH 16
#define HDD 64

typedef __bf16 bf16_t;
typedef __attribute__((ext_vector_type(8))) __bf16 bf16x8;
typedef __attribute__((ext_vector_type(4))) __bf16 bf16x4;
typedef __attribute__((ext_vector_type(4))) float  f32x4;

#define MFMA(a, b, c) __builtin_amdgcn_mfma_f32_16x16x32_bf16((a), (b), (c), 0, 0, 0)

__device__ inline unsigned short bf2us(bf16_t x) {
    union { bf16_t h; unsigned short u; } c; c.h = x; return c.u;
}

__device__ inline void gll16(const bf16_t* g, unsigned short* l) {
    __builtin_amdgcn_global_load_lds(
        (const __attribute__((address_space(1))) void*)g,
        (__attribute__((address_space(3))) void*)l, 16, 0, 0);
}

// Stage [ROWS x 64] bf16 tile into LDS via global_load_lds, chunk-swizzled:
// LDS elem [r][ (c ^ (r&7))*8 + j ].
template<int ROWS>
__device__ inline void stage_tile(const bf16_t* g0, size_t gstride,
                                  unsigned short* lds, int wave, int lane)
{
    const int r8 = lane >> 3;
    const int ck = (lane & 7) ^ r8;
    constexpr int RW = ROWS / 4;
    const bf16_t* g = g0 + (size_t)(wave * RW + r8) * gstride + ck * 8;
    unsigned short* l = lds + wave * RW * 64 + lane * 8;
    #pragma unroll
    for (int i = 0; i < RW / 8; ++i)
        gll16(g + (size_t)(i * 8) * gstride, l + i * 512);
}

// split-s: 40 blocks cover 16 q-tiles x ceil(tiles/8) chunks (chunk = 8 tiles)
__device__ inline void split_decode(int wid, int& qt, int& ch) {
    const int g = (wid >= 24) ? 3 : (wid >= 12) ? 2 : (wid >= 4) ? 1 : 0;
    const int loc = wid - 2 * g * (g + 1);
    qt = 4 * g + loc / (g + 1);
    ch = loc % (g + 1);
}

// ---------------------------------------------------------------------------
// weights fp32->bf16 (wa, wk, wp contiguous in ws)
// ---------------------------------------------------------------------------
__global__ __launch_bounds__(256) void cvt_w(
    const float* __restrict__ wa, const float* __restrict__ wk,
    const float* __restrict__ wp, bf16_t* __restrict__ out)
{
    const size_t NWA = (size_t)2*DDE*DDE;
    const size_t NW  = (size_t)DDE*DDE;
    const size_t e = ((size_t)blockIdx.x * 256 + threadIdx.x) * 4;
    const float* src;
    if (e < NWA)           src = wa + e;
    else if (e < NWA + NW) src = wk + (e - NWA);
    else                   src = wp + (e - NWA - NW);
    float4 v = *(const float4*)src;
    bf16x4 o;
    o[0] = (bf16_t)v.x; o[1] = (bf16_t)v.y;
    o[2] = (bf16_t)v.z; o[3] = (bf16_t)v.w;
    *(bf16x4*)(out + e) = o;
}

// ---------------------------------------------------------------------------
// prep_x: x fp32 -> xb bf16 (natural layout) AND vtg = per-head transpose.
// ---------------------------------------------------------------------------
__global__ __launch_bounds__(256) void prep_x(
    const float* __restrict__ x, bf16_t* __restrict__ xb,
    bf16_t* __restrict__ vtg)
{
    const int t0 = blockIdx.x * 64, h = blockIdx.y, b = blockIdx.z;
    const int tid = threadIdx.x;
    __shared__ __align__(16) bf16_t tile[64 * 64];

    #pragma unroll
    for (int it = 0; it < 2; ++it) {
        const int t = it * 32 + (tid >> 3);
        const int cw = tid & 7;
        const int slot = (cw + (t >> 3)) & 7;
        const float* xp = x + (size_t)(b*TT + t0 + t)*DDE + h*HDD + cw*8;
        float4 v0 = *(const float4*)xp;
        float4 v1 = *(const float4*)(xp + 4);
        bf16x8 v;
        v[0] = (bf16_t)v0.x; v[1] = (bf16_t)v0.y;
        v[2] = (bf16_t)v0.z; v[3] = (bf16_t)v0.w;
        v[4] = (bf16_t)v1.x; v[5] = (bf16_t)v1.y;
        v[6] = (bf16_t)v1.z; v[7] = (bf16_t)v1.w;
        *(bf16x8*)(xb + (size_t)(b*TT + t0 + t)*DDE + h*HDD + cw*8) = v;
        *(bf16x8*)(tile + t*64 + slot*8) = v;
    }
    __syncthreads();
    const int bh = b * NHH + h;
    #pragma unroll
    for (int it = 0; it < 2; ++it) {
        const int d = it * 32 + (tid >> 3);
        const int co = tid & 7;
        const int slot = ((d >> 3) + co) & 7;
        bf16x8 o;
        #pragma unroll
        for (int j = 0; j < 8; ++j)
            o[j] = tile[(co*8 + j)*64 + slot*8 + (d & 7)];
        *(bf16x8*)(vtg + (size_t)(bh*64 + d)*TT + t0 + co*8) = o;
    }
}

// ---------------------------------------------------------------------------
// Fused normalize + E-transpose:
//   yarb[t] = bf16(yo[t]/lsum[t]);  etg[bh][d][t] = x[t][d] - n[t-1][d]
// ---------------------------------------------------------------------------
__global__ __launch_bounds__(256) void norm_build_etg(
    const float* __restrict__ yo, const float* __restrict__ ls,
    const bf16_t* __restrict__ xb, bf16_t* __restrict__ yarb,
    bf16_t* __restrict__ etg)
{
    const int t0 = blockIdx.x * 64, h = blockIdx.y, b = blockIdx.z;
    const int tid = threadIdx.x;
    const int bh = b * NHH + h;
    __shared__ __align__(16) bf16_t tile[64 * 64];

    #pragma unroll
    for (int it = 0; it < 2; ++it) {
        const int t = it * 32 + (tid >> 3);
        const int cw = tid & 7;
        const int slot = (cw + (t >> 3)) & 7;
        const int tg = t0 + t;
        const float inv = 1.f / ls[(size_t)bh*TT + tg];
        const float* yp = yo + (size_t)(b*TT + tg)*DDE + h*HDD + cw*8;
        float4 y0 = *(const float4*)yp;
        float4 y1 = *(const float4*)(yp + 4);
        bf16x8 nb;
        nb[0] = (bf16_t)(y0.x*inv); nb[1] = (bf16_t)(y0.y*inv);
        nb[2] = (bf16_t)(y0.z*inv); nb[3] = (bf16_t)(y0.w*inv);
        nb[4] = (bf16_t)(y1.x*inv); nb[5] = (bf16_t)(y1.y*inv);
        nb[6] = (bf16_t)(y1.z*inv); nb[7] = (bf16_t)(y1.w*inv);
        *(bf16x8*)(yarb + (size_t)(b*TT + tg)*DDE + h*HDD + cw*8) = nb;
        bf16x8 ev;
        if (tg == 0) {
            #pragma unroll
            for (int u = 0; u < 8; ++u) ev[u] = (bf16_t)0.f;
        } else {
            const float invp = 1.f / ls[(size_t)bh*TT + tg - 1];
            const float* ypp = yo + (size_t)(b*TT + tg - 1)*DDE + h*HDD + cw*8;
            float4 p0 = *(const float4*)ypp;
            float4 p1 = *(const float4*)(ypp + 4);
            bf16x8 xv = *(const bf16x8*)(xb + (size_t)(b*TT + tg)*DDE + h*HDD + cw*8);
            ev[0] = (bf16_t)((float)xv[0] - p0.x*invp);
            ev[1] = (bf16_t)((float)xv[1] - p0.y*invp);
            ev[2] = (bf16_t)((float)xv[2] - p0.z*invp);
            ev[3] = (bf16_t)((float)xv[3] - p0.w*invp);
            ev[4] = (bf16_t)((float)xv[4] - p1.x*invp);
            ev[5] = (bf16_t)((float)xv[5] - p1.y*invp);
            ev[6] = (bf16_t)((float)xv[6] - p1.z*invp);
            ev[7] = (bf16_t)((float)xv[7] - p1.w*invp);
        }
        *(bf16x8*)(tile + t*64 + slot*8) = ev;
    }
    __syncthreads();
    #pragma unroll
    for (int it = 0; it < 2; ++it) {
        const int d = it * 32 + (tid >> 3);
        const int co = tid & 7;
        const int slot = ((d >> 3) + co) & 7;
        bf16x8 o;
        #pragma unroll
        for (int j = 0; j < 8; ++j)
            o[j] = tile[(co*8 + j)*64 + slot*8 + (d & 7)];
        *(bf16x8*)(etg + (size_t)(bh*64 + d)*TT + t0 + co*8) = o;
    }
}

// ---------------------------------------------------------------------------
// Fused QKV GEMM, BK=64 swizzled staging (R5).
// ---------------------------------------------------------------------------
__global__ __launch_bounds__(256) void gemm_qkk2(
    const bf16_t* __restrict__ A, const bf16_t* __restrict__ wab,
    const bf16_t* __restrict__ wkb, const float* __restrict__ b_attn,
    const float* __restrict__ b_k2, bf16_t* __restrict__ qkb,
    bf16_t* __restrict__ qab, bf16_t* __restrict__ kcs)
{
    __shared__ __align__(16) unsigned short As[128 * 64];
    __shared__ __align__(16) unsigned short Bs[128 * 64];
    const int tid  = threadIdx.x;
    const int wave = tid >> 6, lane = tid & 63;
    const int l15  = lane & 15, quad = lane >> 4;
    const int bm = blockIdx.y * 128, bn = blockIdx.x * 128;
    const int wm = (wave & 1) * 64, wn = (wave >> 1) * 64;
    const int region = bn >> 10;
    const int K = DDE;

    const bf16_t* W = (region < 2) ? wab + (size_t)bn * K
                                   : wkb + (size_t)(bn - 2048) * K;
    const float* bp = (region < 2) ? b_attn + bn : b_k2 + (bn - 2048);
    const bf16_t* Ab = A + (size_t)bm * K;

    f32x4 acc[4][4];
    #pragma unroll
    for (int i = 0; i < 4; ++i)
        #pragma unroll
        for (int j = 0; j < 4; ++j) acc[i][j] = (f32x4)0.f;

    for (int k0 = 0; k0 < K; k0 += 64) {
        __syncthreads();
        stage_tile<128>(Ab + k0, K, As, wave, lane);
        stage_tile<128>(W  + k0, K, Bs, wave, lane);
        __syncthreads();
        bf16x8 af[4][2], bfr[4][2];
        #pragma unroll
        for (int mt = 0; mt < 4; ++mt)
            #pragma unroll
            for (int kh = 0; kh < 2; ++kh)
                af[mt][kh] = *(const bf16x8*)(As + (wm + mt*16 + l15)*64
                                              + (((kh*4 + quad) ^ (l15 & 7))*8));
        #pragma unroll
        for (int nt = 0; nt < 4; ++nt)
            #pragma unroll
            for (int kh = 0; kh < 2; ++kh)
                bfr[nt][kh] = *(const bf16x8*)(Bs + (wn + nt*16 + l15)*64
                                               + (((kh*4 + quad) ^ (l15 & 7))*8));
        #pragma unroll
        for (int mt = 0; mt < 4; ++mt)
            #pragma unroll
            for (int nt = 0; nt < 4; ++nt) {
                acc[mt][nt] = MFMA(af[mt][0], bfr[nt][0], acc[mt][nt]);
                acc[mt][nt] = MFMA(af[mt][1], bfr[nt][1], acc[mt][nt]);
            }
    }

    #pragma unroll
    for (int nt = 0; nt < 4; ++nt) {
        const int cl = wn + nt*16 + l15;
        const float bj = bp[cl];
        const int cg = bn + cl;
        #pragma unroll
        for (int mt = 0; mt < 4; ++mt)
            #pragma unroll
            for (int r = 0; r < 4; ++r) {
                const int row = bm + wm + mt*16 + quad*4 + r;
                const float v = acc[mt][nt][r] + bj;
                if (region == 0) {
                    qkb[(size_t)row * (2*DDE) + cg] = (bf16_t)(v * 0.180336880f);
                    const float z = v * 0.125f;
                    qab[(size_t)row * DDE + cg] = (bf16_t)((v > 0.f) ? 0.02f*z : z);
                } else if (region == 1) {
                    qkb[(size_t)row * (2*DDE) + cg] = (bf16_t)v;
                } else {
                    const int c2 = cg - 2048;
                    const float kc = 1.f/(1.f + __expf(-v*0.0025f)) - 0.5f;
                    if (((row + 1) & (TT - 1)) != 0)
                        kcs[(size_t)(row + 1) * DDE + c2] = (bf16_t)kc;
                    if ((row & (TT - 1)) == 0)
                        kcs[(size_t)row * DDE + c2] = (bf16_t)0.f;
                }
            }
    }
}

// ---------------------------------------------------------------------------
// proj GEMM with fused combine: A = bf16(yarb + maf) staged via VGPR add
// (manual swizzled LDS write matching stage_tile layout); fp32 out.
// ---------------------------------------------------------------------------
__global__ __launch_bounds__(256) void gemm_proj(
    const bf16_t* __restrict__ yarb, const float* __restrict__ maf,
    const bf16_t* __restrict__ W, const float* __restrict__ bias,
    float* __restrict__ C)
{
    __shared__ __align__(16) unsigned short As[128 * 64];
    __shared__ __align__(16) unsigned short Bs[128 * 64];
    const int tid  = threadIdx.x;
    const int wave = tid >> 6, lane = tid & 63;
    const int l15  = lane & 15, quad = lane >> 4;
    const int bm = blockIdx.y * 128, bn = blockIdx.x * 128;
    const int wm = (wave & 1) * 64, wn = (wave >> 1) * 64;
    const int K = DDE, N = DDE;

    const bf16_t* Wb = W + (size_t)bn * K;
    const int r8 = lane >> 3, ck = (lane & 7) ^ r8;

    f32x4 acc[4][4];
    #pragma unroll
    for (int i = 0; i < 4; ++i)
        #pragma unroll
        for (int j = 0; j < 4; ++j) acc[i][j] = (f32x4)0.f;

    for (int k0 = 0; k0 < K; k0 += 64) {
        __syncthreads();
        // A-tile: yarb + maf, swizzled write matching stage_tile layout
        #pragma unroll
        for (int i = 0; i < 4; ++i) {
            const int row = wave*32 + i*8 + r8;
            const size_t g = (size_t)(bm + row)*DDE + k0 + ck*8;
            bf16x8 a = *(const bf16x8*)(yarb + g);
            float4 m0 = *(const float4*)(maf + g);
            float4 m1 = *(const float4*)(maf + g + 4);
            bf16x8 s;
            s[0] = (bf16_t)((float)a[0] + m0.x);
            s[1] = (bf16_t)((float)a[1] + m0.y);
            s[2] = (bf16_t)((float)a[2] + m0.z);
            s[3] = (bf16_t)((float)a[3] + m0.w);
            s[4] = (bf16_t)((float)a[4] + m1.x);
            s[5] = (bf16_t)((float)a[5] + m1.y);
            s[6] = (bf16_t)((float)a[6] + m1.z);
            s[7] = (bf16_t)((float)a[7] + m1.w);
            *(bf16x8*)((bf16_t*)As + wave*2048 + i*512 + lane*8) = s;
        }
        stage_tile<128>(Wb + k0, K, Bs, wave, lane);
        __syncthreads();
        bf16x8 af[4][2], bfr[4][2];
        #pragma unroll
        for (int mt = 0; mt < 4; ++mt)
            #pragma unroll
            for (int kh = 0; kh < 2; ++kh)
                af[mt][kh] = *(const bf16x8*)(As + (wm + mt*16 + l15)*64
                                              + (((kh*4 + quad) ^ (l15 & 7))*8));
        #pragma unroll
        for (int nt = 0; nt < 4; ++nt)
            #pragma unroll
            for (int kh = 0; kh < 2; ++kh)
                bfr[nt][kh] = *(const bf16x8*)(Bs + (wn + nt*16 + l15)*64
                                               + (((kh*4 + quad) ^ (l15 & 7))*8));
        #pragma unroll
        for (int mt = 0; mt < 4; ++mt)
            #pragma unroll
            for (int nt = 0; nt < 4; ++nt) {
                acc[mt][nt] = MFMA(af[mt][0], bfr[nt][0], acc[mt][nt]);
                acc[mt][nt] = MFMA(af[mt][1], bfr[nt][1], acc[mt][nt]);
            }
    }

    #pragma unroll
    for (int nt = 0; nt < 4; ++nt) {
        const int col = bn + wn + nt*16 + l15;
        const float bj = bias[col] * 2.f;
        #pragma unroll
        for (int mt = 0; mt < 4; ++mt)
            #pragma unroll
            for (int r = 0; r < 4; ++r) {
                const int row = bm + wm + mt*16 + quad*4 + r;
                C[(size_t)row * N + col] = acc[mt][nt][r] + bj;
            }
    }
}

// ---------------------------------------------------------------------------
// AR: fixed-max flash attention, split-s — EXACT R5 structure (separate
// Qs and Pw LDS; known-good).
// ---------------------------------------------------------------------------
__global__ __launch_bounds__(256) void attn_ar_mfma(
    const bf16_t* __restrict__ qkb, const bf16_t* __restrict__ vtg,
    float* __restrict__ yo, float* __restrict__ lsum)
{
    int qt, ch;
    split_decode(39 - (int)blockIdx.x, qt, ch);
    const int h = blockIdx.y, b = blockIdx.z;
    const int tid = threadIdx.x, wave = tid >> 6, lane = tid & 63;
    const int l15 = lane & 15, quad = lane >> 4;
    const int q0 = qt * 128;
    const int bh = b * NHH + h;

    __shared__ __align__(16) unsigned short Qs[128 * 64];
    __shared__ __align__(16) unsigned short Ks[64 * 64];
    __shared__ __align__(16) unsigned short Vs[64 * 64];
    __shared__ __align__(16) unsigned short Pw[4][32 * 72];
    unsigned short* pw = Pw[wave];

    stage_tile<128>(qkb + (size_t)(b*TT + q0) * (2*DDE) + h*HDD, 2*DDE, Qs, wave, lane);
    __syncthreads();

    bf16x8 qf[2][2];
    #pragma unroll
    for (int mt = 0; mt < 2; ++mt)
        #pragma unroll
        for (int kc = 0; kc < 2; ++kc)
            qf[mt][kc] = *(const bf16x8*)(Qs + (wave*32 + mt*16 + l15)*64
                                          + ((kc*4 + quad) ^ (l15 & 7))*8);

    f32x4 o[2][4];
    float lrow[2][4];
    #pragma unroll
    for (int mt = 0; mt < 2; ++mt) {
        #pragma unroll
        for (int nt = 0; nt < 4; ++nt) o[mt][nt] = (f32x4)0.f;
        #pragma unroll
        for (int r = 0; r < 4; ++r) lrow[mt][r] = 0.f;
    }

    const int qw0 = q0 + wave * 32;
    const int kt0 = ch * 8;
    const int kt1 = min(kt0 + 8, 2*qt + 2);
    bool did = false;

    for (int kt = kt0; kt < kt1; ++kt) {
        const int s0 = kt * 64;
        __syncthreads();
        stage_tile<64>(qkb + (size_t)(b*TT + s0)*(2*DDE) + DDE + h*HDD, 2*DDE, Ks, wave, lane);
        stage_tile<64>(vtg + (size_t)(bh*64)*TT + s0, TT, Vs, wave, lane);
        __syncthreads();
        if (s0 > qw0 + 31) continue;
        did = true;

        f32x4 sv[2][4];
        #pragma unroll
        for (int nt = 0; nt < 4; ++nt) {
            const unsigned short* kr = Ks + (nt*16 + l15)*64;
            bf16x8 kb0 = *(const bf16x8*)(kr + ((quad    ) ^ (l15 & 7))*8);
            bf16x8 kb1 = *(const bf16x8*)(kr + ((quad + 4) ^ (l15 & 7))*8);
            #pragma unroll
            for (int mt = 0; mt < 2; ++mt) {
                f32x4 z = (f32x4)0.f;
                z = MFMA(qf[mt][0], kb0, z);
                z = MFMA(qf[mt][1], kb1, z);
                sv[mt][nt] = z;
            }
        }
        const bool domask = (s0 + 63 > qw0);
        #pragma unroll
        for (int mt = 0; mt < 2; ++mt)
            #pragma unroll
            for (int r = 0; r < 4; ++r)
                #pragma unroll
                for (int nt = 0; nt < 4; ++nt) {
                    float p = exp2f(sv[mt][nt][r]);
                    if (domask) {
                        const int qg = qw0 + mt*16 + quad*4 + r;
                        const int sg = s0 + nt*16 + l15;
                        if (sg > qg) p = 0.f;
                    }
                    lrow[mt][r] += p;
                    pw[(mt*16 + quad*4 + r)*72 + nt*16 + l15] = bf2us((bf16_t)p);
                }
        bf16x8 pa[2][2];
        #pragma unroll
        for (int mt = 0; mt < 2; ++mt)
            #pragma unroll
            for (int sc = 0; sc < 2; ++sc)
                pa[mt][sc] = *(const bf16x8*)(pw + (mt*16 + l15)*72 + sc*32 + quad*8);
        #pragma unroll
        for (int nt = 0; nt < 4; ++nt) {
            const unsigned short* vr = Vs + (nt*16 + l15)*64;
            bf16x8 vb0 = *(const bf16x8*)(vr + ((quad    ) ^ (l15 & 7))*8);
            bf16x8 vb1 = *(const bf16x8*)(vr + ((quad + 4) ^ (l15 & 7))*8);
            #pragma unroll
            for (int mt = 0; mt < 2; ++mt) {
                o[mt][nt] = MFMA(pa[mt][0], vb0, o[mt][nt]);
                o[mt][nt] = MFMA(pa[mt][1], vb1, o[mt][nt]);
            }
        }
    }

    if (did) {
        #pragma unroll
        for (int mt = 0; mt < 2; ++mt)
            #pragma unroll
            for (int r = 0; r < 4; ++r) {
                float lv = lrow[mt][r];
                lv += __shfl_xor(lv, 1);
                lv += __shfl_xor(lv, 2);
                lv += __shfl_xor(lv, 4);
                lv += __shfl_xor(lv, 8);
                if (l15 == 0)
                    atomicAdd(lsum + (size_t)bh*TT + qw0 + mt*16 + quad*4 + r, lv);
            }
        #pragma unroll
        for (int mt = 0; mt < 2; ++mt)
            #pragma unroll
            for (int nt = 0; nt < 4; ++nt)
                #pragma unroll
                for (int r = 0; r < 4; ++r) {
                    const int row = qw0 + mt*16 + quad*4 + r;
                    const int col = h*HDD + nt*16 + l15;
                    atomicAdd(yo + (size_t)(b*TT + row)*DDE + col, o[mt][nt][r]);
                }
    }
}

// ---------------------------------------------------------------------------
// MA: linear causal attention, split-s — EXACT R5 structure.
// ---------------------------------------------------------------------------
__global__ __launch_bounds__(256) void attn_ma_mfma(
    const bf16_t* __restrict__ qab, const bf16_t* __restrict__ kcs,
    const bf16_t* __restrict__ etg, float* __restrict__ ma)
{
    int qt, ch;
    split_decode(39 - (int)blockIdx.x, qt, ch);
    const int h = blockIdx.y, b = blockIdx.z;
    const int tid = threadIdx.x, wave = tid >> 6, lane = tid & 63;
    const int l15 = lane & 15, quad = lane >> 4;
    const int q0 = qt * 128;
    const int bh = b * NHH + h;

    __shared__ __align__(16) unsigned short Qs[128 * 64];
    __shared__ __align__(16) unsigned short Ks[64 * 64];
    __shared__ __align__(16) unsigned short Es[64 * 64];
    __shared__ __align__(16) unsigned short Pw[4][32 * 72];
    __shared__ float Rl[128];
    unsigned short* pw = Pw[wave];

    stage_tile<128>(qab + (size_t)(b*TT + q0)*DDE + h*HDD, DDE, Qs, wave, lane);
    __syncthreads();
    if (tid < 128) {
        float s = 0.f;
        #pragma unroll
        for (int c = 0; c < 8; ++c) {
            bf16x8 v = *(const bf16x8*)(Qs + tid*64 + c*8);
            #pragma unroll
            for (int u = 0; u < 8; ++u) s += (float)v[u];
        }
        Rl[tid] = s;
    }
    __syncthreads();

    bf16x8 qf[2][2];
    float Rr[2][4];
    #pragma unroll
    for (int mt = 0; mt < 2; ++mt) {
        #pragma unroll
        for (int kc = 0; kc < 2; ++kc)
            qf[mt][kc] = *(const bf16x8*)(Qs + (wave*32 + mt*16 + l15)*64
                                          + ((kc*4 + quad) ^ (l15 & 7))*8);
        #pragma unroll
        for (int r = 0; r < 4; ++r)
            Rr[mt][r] = 0.5f * Rl[wave*32 + mt*16 + quad*4 + r];
    }

    f32x4 o[2][4];
    #pragma unroll
    for (int mt = 0; mt < 2; ++mt)
        #pragma unroll
        for (int nt = 0; nt < 4; ++nt) o[mt][nt] = (f32x4)0.f;

    const int qw0 = q0 + wave * 32;
    const int kt0 = ch * 8;
    const int kt1 = min(kt0 + 8, 2*qt + 2);
    bool did = false;

    for (int kt = kt0; kt < kt1; ++kt) {
        const int s0 = kt * 64;
        __syncthreads();
        stage_tile<64>(kcs + (size_t)(b*TT + s0)*DDE + h*HDD, DDE, Ks, wave, lane);
        stage_tile<64>(etg + (size_t)(bh*64)*TT + s0, TT, Es, wave, lane);
        __syncthreads();
        if (s0 > qw0 + 31) continue;
        did = true;

        f32x4 sv[2][4];
        #pragma unroll
        for (int nt = 0; nt < 4; ++nt) {
            const unsigned short* kr = Ks + (nt*16 + l15)*64;
            bf16x8 kb0 = *(const bf16x8*)(kr + ((quad    ) ^ (l15 & 7))*8);
            bf16x8 kb1 = *(const bf16x8*)(kr + ((quad + 4) ^ (l15 & 7))*8);
            #pragma unroll
            for (int mt = 0; mt < 2; ++mt) {
                f32x4 z = (f32x4)0.f;
                z = MFMA(qf[mt][0], kb0, z);
                z = MFMA(qf[mt][1], kb1, z);
                sv[mt][nt] = z;
            }
        }
        const bool domask = (s0 + 63 > qw0);
        const bool m0 = (kt == 0);
        #pragma unroll
        for (int mt = 0; mt < 2; ++mt)
            #pragma unroll
            for (int r = 0; r < 4; ++r)
                #pragma unroll
                for (int nt = 0; nt < 4; ++nt) {
                    const int sg = s0 + nt*16 + l15;
                    float p = sv[mt][nt][r] + Rr[mt][r];
                    if (m0 && sg == 0) p = 0.f;
                    if (domask) {
                        const int qg = qw0 + mt*16 + quad*4 + r;
                        if (sg > qg) p = 0.f;
                    }
                    pw[(mt*16 + quad*4 + r)*72 + nt*16 + l15] = bf2us((bf16_t)p);
                }
        bf16x8 pa[2][2];
        #pragma unroll
        for (int mt = 0; mt < 2; ++mt)
            #pragma unroll
            for (int sc = 0; sc < 2; ++sc)
                pa[mt][sc] = *(const bf16x8*)(pw + (mt*16 + l15)*72 + sc*32 + quad*8);
        #pragma unroll
        for (int nt = 0; nt < 4; ++nt) {
            const unsigned short* er = Es + (nt*16 + l15)*64;
            bf16x8 eb0 = *(const bf16x8*)(er + ((quad    ) ^ (l15 & 7))*8);
            bf16x8 eb1 = *(const bf16x8*)(er + ((quad + 4) ^ (l15 & 7))*8);
            #pragma unroll
            for (int mt = 0; mt < 2; ++mt) {
                o[mt][nt] = MFMA(pa[mt][0], eb0, o[mt][nt]);
                o[mt][nt] = MFMA(pa[mt][1], eb1, o[mt][nt]);
            }
        }
    }

    if (did) {
        #pragma unroll
        for (int mt = 0; mt < 2; ++mt)
            #pragma unroll
            for (int nt = 0; nt < 4; ++nt)
                #pragma unroll
                for (int r = 0; r < 4; ++r) {
                    const int row = qw0 + mt*16 + quad*4 + r;
                    const int col = h*HDD + nt*16 + l15;
                    atomicAdd(ma + (size_t)(b*TT + row)*DDE + col, o[mt][nt][r]);
                }
    }
}

// ---------------------------------------------------------------------------
extern "C" void kernel_launch(void* const* d_in, const int* in_sizes, int n_in,
                              void* d_out, int out_size, void* d_ws, size_t ws_size,
                              hipStream_t stream)
{
    const float* x      = (const float*)d_in[0];
    const float* w_attn = (const float*)d_in[1];
    const float* b_attn = (const float*)d_in[2];
    const float* w_k2   = (const float*)d_in[3];
    const float* b_k2   = (const float*)d_in[4];
    const float* w_proj = (const float*)d_in[5];
    const float* b_proj = (const float*)d_in[6];

    const size_t NX  = (size_t)BB*TT*DDE;
    const size_t NWA = (size_t)2*DDE*DDE;
    const size_t NW  = (size_t)DDE*DDE;
    const size_t NQK = (size_t)BB*TT*2*DDE;

    bf16_t* xb   = (bf16_t*)d_ws;
    bf16_t* wab  = xb   + NX;
    bf16_t* wkb  = wab  + NWA;
    bf16_t* wpb  = wkb  + NW;
    bf16_t* qkb  = wpb  + NW;      // aliased by maf (f32) after attn_ar
    bf16_t* qab  = qkb  + NQK;
    bf16_t* kcs  = qab  + NX;
    bf16_t* vtg  = kcs  + NX;      // aliased by etg after attn_ar
    float*  yo   = (float*)(vtg + NX);
    bf16_t* yarb = (bf16_t*)(yo + NX);
    float*  lsum = (float*)wab;    // aliases wab after gemm_qkk2
    float*  maf  = (float*)qkb;
    bf16_t* etg  = vtg;

    hipMemsetAsync(yo, 0, NX * sizeof(float), stream);

    cvt_w<<<(NWA + 2*NW) / 1024, 256, 0, stream>>>(w_attn, w_k2, w_proj, wab);
    prep_x<<<dim3(TT/64, NHH, BB), 256, 0, stream>>>(x, xb, vtg);

    const int M = BB * TT;
    gemm_qkk2<<<dim3(24, M/128), 256, 0, stream>>>(xb, wab, wkb, b_attn, b_k2,
                                                    qkb, qab, kcs);
    hipMemsetAsync(lsum, 0, (size_t)BB*NHH*TT * sizeof(float), stream);

    attn_ar_mfma<<<dim3(40, NHH, BB), 256, 0, stream>>>(qkb, vtg, yo, lsum);
    norm_build_etg<<<dim3(TT/64, NHH, BB), 256, 0, stream>>>(yo, lsum, xb, yarb, etg);

    hipMemsetAsync(maf, 0, NX * sizeof(float), stream);
    attn_ma_mfma<<<dim3(40, NHH, BB), 256, 0, stream>>>(qab, kcs, etg, maf);

    gemm_proj<<<dim3(DDE/128, M/128), 256, 0, stream>>>(yarb, maf, wpb, b_proj,
                                                        (float*)d_out);
}